// Round 7
// baseline (470.480 us; speedup 1.0000x reference)
//
#include <hip/hip_runtime.h>

#define DM   1024
#define DI   2048
#define DSZ  16
#define DTR  64
#define BB   2
#define LL   2048
#define MM   (BB*LL)   // 4096
#define SEG  16
#define TSEG (LL/SEG)  // 128
#define NCH  (BB*DI)   // 4096 total channels

using bfrag8 = __attribute__((ext_vector_type(8))) short;
using facc4  = __attribute__((ext_vector_type(4))) float;

__device__ __forceinline__ unsigned short f2bf(float f) {
  unsigned int u = __float_as_uint(f);
  u += 0x7fffu + ((u >> 16) & 1u);
  return (unsigned short)(u >> 16);
}

__device__ __forceinline__ float sigmoidf_(float x) { return 1.f / (1.f + __expf(-x)); }
__device__ __forceinline__ float softplusf_(float x) { return (x > 20.f) ? x : log1pf(__expf(x)); }

__device__ __forceinline__ void gload16(const void* g, void* l) {
  __builtin_amdgcn_global_load_lds(
      (__attribute__((address_space(1))) void*)(g),
      (__attribute__((address_space(3))) void*)(l), 16, 0, 0);
}

// ---------------- elementwise converts ----------------

__global__ __launch_bounds__(256) void cvt_bf16(const float* __restrict__ s,
                                                unsigned short* __restrict__ d, int n) {
  int i = (blockIdx.x * 256 + threadIdx.x) * 4;
  if (i + 3 < n) {
    float4 v = *(const float4*)(s + i);
    ushort4 o;
    o.x = f2bf(v.x); o.y = f2bf(v.y); o.z = f2bf(v.z); o.w = f2bf(v.w);
    *(ushort4*)(d + i) = o;
  }
}

// src f32 [R][C] -> dst bf16 [C][R]; R,C multiples of 32
__global__ __launch_bounds__(256) void transpose_cvt(const float* __restrict__ src,
                                                     unsigned short* __restrict__ dst,
                                                     int R, int C) {
  __shared__ float tile[32][33];
  int c0 = blockIdx.x * 32, r0 = blockIdx.y * 32;
  for (int i = threadIdx.y; i < 32; i += 8)
    tile[i][threadIdx.x] = src[(size_t)(r0 + i) * C + c0 + threadIdx.x];
  __syncthreads();
  for (int i = threadIdx.y; i < 32; i += 8)
    dst[(size_t)(c0 + i) * R + r0 + threadIdx.x] = f2bf(tile[threadIdx.x][i]);
}

__global__ __launch_bounds__(256) void extract_dr(const float* __restrict__ dbc,
                                                  unsigned short* __restrict__ dr) {
  int i = blockIdx.x * 256 + threadIdx.x;
  if (i < MM * DTR) {
    int row = i >> 6, c = i & 63;
    dr[i] = f2bf(dbc[(size_t)row * 96 + c]);
  }
}

// ---------------- depthwise causal conv + silu ----------------
__global__ __launch_bounds__(256) void conv_silu(const float* __restrict__ xr,
                                                 const float* __restrict__ cw,
                                                 const float* __restrict__ cb,
                                                 float* __restrict__ uf,
                                                 unsigned short* __restrict__ ubf) {
  const int d = blockIdx.x * 256 + threadIdx.x;
  const int b = blockIdx.z;
  const int t0 = blockIdx.y * 64;
  const float w0 = cw[d * 4 + 0], w1 = cw[d * 4 + 1], w2 = cw[d * 4 + 2], w3 = cw[d * 4 + 3];
  const float bias = cb[d];
  const size_t base = ((size_t)b * LL) * (2 * DI) + d;
  float xm3 = (t0 >= 3) ? xr[base + (size_t)(t0 - 3) * (2 * DI)] : 0.f;
  float xm2 = (t0 >= 2) ? xr[base + (size_t)(t0 - 2) * (2 * DI)] : 0.f;
  float xm1 = (t0 >= 1) ? xr[base + (size_t)(t0 - 1) * (2 * DI)] : 0.f;
  for (int t = t0; t < t0 + 64; ++t) {
    float x0 = xr[base + (size_t)t * (2 * DI)];
    float a = bias + w0 * xm3 + w1 * xm2 + w2 * xm1 + w3 * x0;
    float uu = a * sigmoidf_(a);
    size_t oi = ((size_t)b * LL + t) * DI + d;
    uf[oi] = uu;
    ubf[oi] = f2bf(uu);
    xm3 = xm2; xm2 = xm1; xm1 = x0;
  }
}

// ---------------- bf16 MFMA GEMM:  C[M][N] = A[M][K] * Bt[N][K]^T ----------------
// EPI: 0 = store f32; 1 = softplus(v + bias[col]); 2 = atomicAdd (split-K)
template<int BM, int BN, int WMN, int WNN, int MF, int NF, int EPI>
__global__ __launch_bounds__(256, 2) void gemm_bf16(const unsigned short* __restrict__ A,
                                                    const unsigned short* __restrict__ Bt,
                                                    float* __restrict__ C,
                                                    const float* __restrict__ bias,
                                                    int M, int N, int K, int kLen) {
  static_assert(WMN * WNN == 4 && WMN * MF * 16 == BM && WNN * NF * 16 == BN, "geom");
  __shared__ unsigned short smem[(BM + BN) * 32];
  unsigned short* As = smem;
  unsigned short* Bs = smem + BM * 32;
  const int tid = threadIdx.x;
  const int wave = tid >> 6, lane = tid & 63;
  const int tM = blockIdx.y * BM, tN = blockIdx.x * BN;
  const int k0 = blockIdx.z * kLen;
  const int lrow = lane >> 2, lq = lane & 3;
  const int wm = wave / WNN, wn = wave % WNN;
  const int fr = lane & 15, kg = lane >> 4;

  facc4 acc[MF][NF];
#pragma unroll
  for (int mi = 0; mi < MF; ++mi)
#pragma unroll
    for (int ni = 0; ni < NF; ++ni)
#pragma unroll
      for (int r = 0; r < 4; ++r) acc[mi][ni][r] = 0.f;

  for (int kk = k0; kk < k0 + kLen; kk += 32) {
    __syncthreads();
    for (int r = wave; r < BM / 16; r += 4) {
      int row = r * 16 + lrow;
      int lcb = (lq ^ ((row >> 1) & 3)) << 4;
      const char* src = (const char*)(A + (size_t)(tM + row) * K + kk) + lcb;
      gload16(src, (char*)As + r * 1024);
    }
    for (int r = wave; r < BN / 16; r += 4) {
      int row = r * 16 + lrow;
      int lcb = (lq ^ ((row >> 1) & 3)) << 4;
      const char* src = (const char*)(Bt + (size_t)(tN + row) * K + kk) + lcb;
      gload16(src, (char*)Bs + r * 1024);
    }
    __syncthreads();

    bfrag8 af[MF], bfr[NF];
#pragma unroll
    for (int mi = 0; mi < MF; ++mi) {
      int row = wm * (MF * 16) + mi * 16 + fr;
      af[mi] = *(const bfrag8*)((const char*)As + row * 64 + ((kg ^ ((row >> 1) & 3)) << 4));
    }
#pragma unroll
    for (int ni = 0; ni < NF; ++ni) {
      int row = wn * (NF * 16) + ni * 16 + fr;
      bfr[ni] = *(const bfrag8*)((const char*)Bs + row * 64 + ((kg ^ ((row >> 1) & 3)) << 4));
    }
#pragma unroll
    for (int mi = 0; mi < MF; ++mi)
#pragma unroll
      for (int ni = 0; ni < NF; ++ni)
        acc[mi][ni] = __builtin_amdgcn_mfma_f32_16x16x32_bf16(af[mi], bfr[ni], acc[mi][ni], 0, 0, 0);
  }

  const int orow = tM + wm * (MF * 16), ocol = tN + wn * (NF * 16);
#pragma unroll
  for (int mi = 0; mi < MF; ++mi)
#pragma unroll
    for (int ni = 0; ni < NF; ++ni)
#pragma unroll
      for (int r = 0; r < 4; ++r) {
        int row = orow + mi * 16 + kg * 4 + r;
        int col = ocol + ni * 16 + fr;
        float v = acc[mi][ni][r];
        size_t idx = (size_t)row * N + col;
        if (EPI == 0)      C[idx] = v;
        else if (EPI == 1) C[idx] = softplusf_(v + bias[col]);
        else               atomicAdd(&C[idx], v);
      }
}

// ---------------- segmented selective scan ----------------
// Pass 1: per (16-channel group, segment): local scan with h0=0 over TSEG steps.
// Stores P = prod(dA), Q = local h_end.  pq layout: [P|Q][seg][NCH][DSZ]
__global__ __launch_bounds__(256) void scan_pass1(const float* __restrict__ delta,
                                                  const float* __restrict__ dbc,
                                                  const float* __restrict__ u,
                                                  const float* __restrict__ A_log,
                                                  float* __restrict__ pq) {
  const int tid = threadIdx.x;
  const int ci = tid >> 4, n = tid & 15;
  const int lt = ci, lc = n;
  const int ch0 = blockIdx.x * 16;
  const int b = ch0 / DI, d0 = ch0 % DI;
  const int seg = blockIdx.y;
  const float Adn = -__expf(A_log[(d0 + ci) * DSZ + n]);
  __shared__ float sdel[2][16][16], su[2][16][16], sB[2][16][16];
  const size_t rb = (size_t)b * LL + (size_t)seg * TSEG;

  {
    const size_t row = rb + lt;
    sdel[0][lt][lc] = delta[row * DI + d0 + lc];
    su[0][lt][lc]   = u[row * DI + d0 + lc];
    sB[0][lt][lc]   = dbc[row * 96 + DTR + lc];
  }
  __syncthreads();

  float h = 0.f, p = 1.f;
  const int nch = TSEG / 16;
  for (int c = 0; c < nch; ++c) {
    const int cur = c & 1;
    float r0 = 0, r1 = 0, r3 = 0;
    const bool nxt = (c + 1) < nch;
    if (nxt) {
      const size_t row = rb + (size_t)(c + 1) * 16 + lt;
      r0 = delta[row * DI + d0 + lc];
      r1 = u[row * DI + d0 + lc];
      r3 = dbc[row * 96 + DTR + lc];
    }
#pragma unroll
    for (int tt = 0; tt < 16; ++tt) {
      float dl = sdel[cur][tt][ci];
      float uu = su[cur][tt][ci];
      float dA = __expf(dl * Adn);
      float dBu = dl * sB[cur][tt][n] * uu;
      h = __builtin_fmaf(dA, h, dBu);
      p *= dA;
    }
    if (nxt) {  // writes target the other buffer; prior barrier already fenced its readers
      const int nb = cur ^ 1;
      sdel[nb][lt][lc] = r0; su[nb][lt][lc] = r1; sB[nb][lt][lc] = r3;
    }
    __syncthreads();
  }
  const size_t base = ((size_t)seg * NCH + ch0 + ci) * DSZ + n;
  pq[base] = p;
  pq[(size_t)SEG * NCH * DSZ + base] = h;
}

// Prefix: per (channel, state): chain the SEG segment transfer functions.
__global__ __launch_bounds__(256) void scan_prefix(const float* __restrict__ pq,
                                                   float* __restrict__ hinit) {
  const int i = blockIdx.x * 256 + threadIdx.x;  // i = ch*DSZ + n
  const size_t stride = (size_t)NCH * DSZ;
  float h = 0.f;
#pragma unroll
  for (int s = 0; s < SEG; ++s) {
    hinit[(size_t)s * stride + i] = h;
    float P = pq[(size_t)s * stride + i];
    float Q = pq[(size_t)SEG * stride + (size_t)s * stride + i];
    h = __builtin_fmaf(P, h, Q);
  }
}

// Pass 2: per (16-channel group, segment): true scan from h_init, emit y (bf16).
// n-reduction via shfl_xor (width 16) into sy[16][16]; no sp transpose buffer.
__global__ __launch_bounds__(256) void scan_pass2(const float* __restrict__ delta,
                                                  const float* __restrict__ dbc,
                                                  const float* __restrict__ u,
                                                  const float* __restrict__ xr,
                                                  const float* __restrict__ A_log,
                                                  const float* __restrict__ Dv,
                                                  const float* __restrict__ hinit,
                                                  unsigned short* __restrict__ ybf) {
  const int tid = threadIdx.x;
  const int ci = tid >> 4, n = tid & 15;
  const int lt = ci, lc = n;
  const int ch0 = blockIdx.x * 16;
  const int b = ch0 / DI, d0 = ch0 % DI;
  const int seg = blockIdx.y;
  const float Adn = -__expf(A_log[(d0 + ci) * DSZ + n]);
  const float Dd = Dv[d0 + lc];
  __shared__ float sdel[2][16][16], su[2][16][16], sres[2][16][16], sB[2][16][16], sC[2][16][16];
  __shared__ float sy[16][16];
  const size_t rb = (size_t)b * LL + (size_t)seg * TSEG;

  float h = hinit[((size_t)seg * NCH + ch0 + ci) * DSZ + n];

  {
    const size_t row = rb + lt;
    sdel[0][lt][lc] = delta[row * DI + d0 + lc];
    su[0][lt][lc]   = u[row * DI + d0 + lc];
    sres[0][lt][lc] = xr[row * (2 * DI) + DI + d0 + lc];
    sB[0][lt][lc]   = dbc[row * 96 + DTR + lc];
    sC[0][lt][lc]   = dbc[row * 96 + DTR + DSZ + lc];
  }
  __syncthreads();

  const int nch = TSEG / 16;
  for (int c = 0; c < nch; ++c) {
    const int cur = c & 1;
    float r0 = 0, r1 = 0, r2 = 0, r3 = 0, r4 = 0;
    const bool nxt = (c + 1) < nch;
    if (nxt) {
      const size_t row = rb + (size_t)(c + 1) * 16 + lt;
      r0 = delta[row * DI + d0 + lc];
      r1 = u[row * DI + d0 + lc];
      r2 = xr[row * (2 * DI) + DI + d0 + lc];
      r3 = dbc[row * 96 + DTR + lc];
      r4 = dbc[row * 96 + DTR + DSZ + lc];
    }
#pragma unroll
    for (int tt = 0; tt < 16; ++tt) {
      float dl = sdel[cur][tt][ci];
      float uu = su[cur][tt][ci];
      float dA = __expf(dl * Adn);
      float dBu = dl * sB[cur][tt][n] * uu;
      h = __builtin_fmaf(dA, h, dBu);
      float py = h * sC[cur][tt][n];
      py += __shfl_xor(py, 1, 16);
      py += __shfl_xor(py, 2, 16);
      py += __shfl_xor(py, 4, 16);
      py += __shfl_xor(py, 8, 16);
      if (n == 0) sy[tt][ci] = py;
    }
    __syncthreads();
    {
      float ysum = sy[lt][lc];
      float uu = su[cur][lt][lc];
      float rs = sres[cur][lt][lc];
      float yv = (ysum + uu * Dd) * (rs * sigmoidf_(rs));
      const size_t row = rb + (size_t)c * 16 + lt;
      ybf[row * DI + d0 + lc] = f2bf(yv);
    }
    if (nxt) {
      const int nb = cur ^ 1;
      sdel[nb][lt][lc] = r0; su[nb][lt][lc] = r1; sres[nb][lt][lc] = r2;
      sB[nb][lt][lc] = r3; sC[nb][lt][lc] = r4;
    }
    __syncthreads();
  }
}

// ---------------- launcher ----------------
extern "C" void kernel_launch(void* const* d_in, const int* in_sizes, int n_in,
                              void* d_out, int out_size, void* d_ws, size_t ws_size,
                              hipStream_t stream) {
  const float* x     = (const float*)d_in[0];
  const float* W_in  = (const float*)d_in[1];
  const float* convw = (const float*)d_in[2];
  const float* convb = (const float*)d_in[3];
  const float* W_x   = (const float*)d_in[4];
  const float* W_dt  = (const float*)d_in[5];
  const float* b_dt  = (const float*)d_in[6];
  const float* A_log = (const float*)d_in[7];
  const float* Dv    = (const float*)d_in[8];
  const float* W_out = (const float*)d_in[9];
  float* out = (float*)d_out;

  char* ws = (char*)d_ws;
  size_t off = 0;
  auto alloc = [&](size_t bytes) { char* p = ws + off; off += (bytes + 255) & ~(size_t)255; return p; };
  unsigned short* xbf   = (unsigned short*)alloc((size_t)MM * DM * 2);
  unsigned short* Wint  = (unsigned short*)alloc((size_t)(2 * DI) * DM * 2);
  float*          xr    = (float*)alloc((size_t)MM * (2 * DI) * 4);
  float*          uf    = (float*)alloc((size_t)MM * DI * 4);
  unsigned short* ubf   = (unsigned short*)alloc((size_t)MM * DI * 2);
  unsigned short* Wxt   = (unsigned short*)alloc((size_t)96 * DI * 2);
  float*          dbc   = (float*)alloc((size_t)MM * 96 * 4);
  unsigned short* drbf  = (unsigned short*)alloc((size_t)MM * DTR * 2);
  unsigned short* Wdtt  = (unsigned short*)alloc((size_t)DI * DTR * 2);
  float*          delta = (float*)alloc((size_t)MM * DI * 4);
  unsigned short* ybf   = (unsigned short*)alloc((size_t)MM * DI * 2);
  unsigned short* Woutt = (unsigned short*)alloc((size_t)DM * DI * 2);
  float*          pq    = (float*)alloc((size_t)2 * SEG * NCH * DSZ * 4);
  float*          hinit = (float*)alloc((size_t)SEG * NCH * DSZ * 4);

  cvt_bf16<<<(MM * DM / 4) / 256, 256, 0, stream>>>(x, xbf, MM * DM);
  transpose_cvt<<<dim3((2 * DI) / 32, DM / 32), dim3(32, 8), 0, stream>>>(W_in, Wint, DM, 2 * DI);
  transpose_cvt<<<dim3(96 / 32, DI / 32), dim3(32, 8), 0, stream>>>(W_x, Wxt, DI, 96);
  transpose_cvt<<<dim3(DI / 32, DTR / 32), dim3(32, 8), 0, stream>>>(W_dt, Wdtt, DTR, DI);
  transpose_cvt<<<dim3(DM / 32, DI / 32), dim3(32, 8), 0, stream>>>(W_out, Woutt, DI, DM);

  // xr = x @ W_in   (M=4096, N=4096, K=1024)
  gemm_bf16<128, 128, 2, 2, 4, 4, 0><<<dim3((2 * DI) / 128, MM / 128, 1), 256, 0, stream>>>(
      xbf, Wint, xr, nullptr, MM, 2 * DI, DM, DM);

  // u = silu(conv(xi))
  conv_silu<<<dim3(DI / 256, LL / 64, BB), 256, 0, stream>>>(xr, convw, convb, uf, ubf);

  // dbc = u @ W_x   (M=4096, N=96, K=2048) split-K=8
  hipMemsetAsync(dbc, 0, (size_t)MM * 96 * 4, stream);
  gemm_bf16<128, 96, 4, 1, 2, 6, 2><<<dim3(1, MM / 128, 8), 256, 0, stream>>>(
      ubf, Wxt, dbc, nullptr, MM, 96, DI, DI / 8);

  extract_dr<<<(MM * DTR) / 256, 256, 0, stream>>>(dbc, drbf);

  // delta = softplus(delta_r @ W_dt + b_dt)   (M=4096, N=2048, K=64)
  gemm_bf16<128, 128, 2, 2, 4, 4, 1><<<dim3(DI / 128, MM / 128, 1), 256, 0, stream>>>(
      drbf, Wdtt, delta, b_dt, MM, DI, DTR, DTR);

  // segmented selective scan
  scan_pass1<<<dim3(NCH / 16, SEG), 256, 0, stream>>>(delta, dbc, uf, A_log, pq);
  scan_prefix<<<(NCH * DSZ) / 256, 256, 0, stream>>>(pq, hinit);
  scan_pass2<<<dim3(NCH / 16, SEG), 256, 0, stream>>>(delta, dbc, uf, xr, A_log, Dv, hinit, ybf);

  // out = y @ W_out   (M=4096, N=1024, K=2048)
  gemm_bf16<128, 128, 2, 2, 4, 4, 0><<<dim3(DM / 128, MM / 128, 1), 256, 0, stream>>>(
      ybf, Woutt, out, nullptr, MM, DM, DI, DI);
}

// Round 9
// 405.585 us; speedup vs baseline: 1.1600x; 1.1600x over previous
//
#include <hip/hip_runtime.h>

#define DM   1024
#define DI   2048
#define DSZ  16
#define DTR  64
#define BB   2
#define LL   2048
#define MM   (BB*LL)   // 4096
#define SEG  32
#define TSEG (LL/SEG)  // 64
#define NCH  (BB*DI)   // 4096 total channels

using bfrag8 = __attribute__((ext_vector_type(8))) short;
using facc4  = __attribute__((ext_vector_type(4))) float;

__device__ __forceinline__ unsigned short f2bf(float f) {
  unsigned int u = __float_as_uint(f);
  u += 0x7fffu + ((u >> 16) & 1u);
  return (unsigned short)(u >> 16);
}

__device__ __forceinline__ float sigmoidf_(float x) { return 1.f / (1.f + __expf(-x)); }
__device__ __forceinline__ float softplusf_(float x) { return (x > 20.f) ? x : log1pf(__expf(x)); }

__device__ __forceinline__ void gload16(const void* g, void* l) {
  __builtin_amdgcn_global_load_lds(
      (__attribute__((address_space(1))) void*)(g),
      (__attribute__((address_space(3))) void*)(l), 16, 0, 0);
}

// ---------------- elementwise converts ----------------

__global__ __launch_bounds__(256) void cvt_bf16(const float* __restrict__ s,
                                                unsigned short* __restrict__ d, int n) {
  int i = (blockIdx.x * 256 + threadIdx.x) * 4;
  if (i + 3 < n) {
    float4 v = *(const float4*)(s + i);
    ushort4 o;
    o.x = f2bf(v.x); o.y = f2bf(v.y); o.z = f2bf(v.z); o.w = f2bf(v.w);
    *(ushort4*)(d + i) = o;
  }
}

// src f32 [R][C] -> dst bf16 [C][R]; R,C multiples of 32
__global__ __launch_bounds__(256) void transpose_cvt(const float* __restrict__ src,
                                                     unsigned short* __restrict__ dst,
                                                     int R, int C) {
  __shared__ float tile[32][33];
  int c0 = blockIdx.x * 32, r0 = blockIdx.y * 32;
  for (int i = threadIdx.y; i < 32; i += 8)
    tile[i][threadIdx.x] = src[(size_t)(r0 + i) * C + c0 + threadIdx.x];
  __syncthreads();
  for (int i = threadIdx.y; i < 32; i += 8)
    dst[(size_t)(c0 + i) * R + r0 + threadIdx.x] = f2bf(tile[threadIdx.x][i]);
}

__global__ __launch_bounds__(256) void extract_dr(const float* __restrict__ dbc,
                                                  unsigned short* __restrict__ dr) {
  int i = blockIdx.x * 256 + threadIdx.x;
  if (i < MM * DTR) {
    int row = i >> 6, c = i & 63;
    dr[i] = f2bf(dbc[(size_t)row * 96 + c]);
  }
}

// ---------------- depthwise causal conv + silu ----------------
__global__ __launch_bounds__(256) void conv_silu(const float* __restrict__ xr,
                                                 const float* __restrict__ cw,
                                                 const float* __restrict__ cb,
                                                 float* __restrict__ uf,
                                                 unsigned short* __restrict__ ubf) {
  const int d = blockIdx.x * 256 + threadIdx.x;
  const int b = blockIdx.z;
  const int t0 = blockIdx.y * 64;
  const float w0 = cw[d * 4 + 0], w1 = cw[d * 4 + 1], w2 = cw[d * 4 + 2], w3 = cw[d * 4 + 3];
  const float bias = cb[d];
  const size_t base = ((size_t)b * LL) * (2 * DI) + d;
  float xm3 = (t0 >= 3) ? xr[base + (size_t)(t0 - 3) * (2 * DI)] : 0.f;
  float xm2 = (t0 >= 2) ? xr[base + (size_t)(t0 - 2) * (2 * DI)] : 0.f;
  float xm1 = (t0 >= 1) ? xr[base + (size_t)(t0 - 1) * (2 * DI)] : 0.f;
  for (int t = t0; t < t0 + 64; ++t) {
    float x0 = xr[base + (size_t)t * (2 * DI)];
    float a = bias + w0 * xm3 + w1 * xm2 + w2 * xm1 + w3 * x0;
    float uu = a * sigmoidf_(a);
    size_t oi = ((size_t)b * LL + t) * DI + d;
    uf[oi] = uu;
    ubf[oi] = f2bf(uu);
    xm3 = xm2; xm2 = xm1; xm1 = x0;
  }
}

// ---------------- bf16 MFMA GEMM:  C[M][N] = A[M][K] * Bt[N][K]^T ----------------
// EPI: 0 = store f32; 1 = softplus(v + bias[col]); 2 = atomicAdd (split-K)
template<int BM, int BN, int WMN, int WNN, int MF, int NF, int EPI>
__global__ __launch_bounds__(256, 2) void gemm_bf16(const unsigned short* __restrict__ A,
                                                    const unsigned short* __restrict__ Bt,
                                                    float* __restrict__ C,
                                                    const float* __restrict__ bias,
                                                    int M, int N, int K, int kLen) {
  static_assert(WMN * WNN == 4 && WMN * MF * 16 == BM && WNN * NF * 16 == BN, "geom");
  __shared__ unsigned short smem[(BM + BN) * 32];
  unsigned short* As = smem;
  unsigned short* Bs = smem + BM * 32;
  const int tid = threadIdx.x;
  const int wave = tid >> 6, lane = tid & 63;
  const int tM = blockIdx.y * BM, tN = blockIdx.x * BN;
  const int k0 = blockIdx.z * kLen;
  const int lrow = lane >> 2, lq = lane & 3;
  const int wm = wave / WNN, wn = wave % WNN;
  const int fr = lane & 15, kg = lane >> 4;

  facc4 acc[MF][NF];
#pragma unroll
  for (int mi = 0; mi < MF; ++mi)
#pragma unroll
    for (int ni = 0; ni < NF; ++ni)
#pragma unroll
      for (int r = 0; r < 4; ++r) acc[mi][ni][r] = 0.f;

  for (int kk = k0; kk < k0 + kLen; kk += 32) {
    __syncthreads();
    for (int r = wave; r < BM / 16; r += 4) {
      int row = r * 16 + lrow;
      int lcb = (lq ^ ((row >> 1) & 3)) << 4;
      const char* src = (const char*)(A + (size_t)(tM + row) * K + kk) + lcb;
      gload16(src, (char*)As + r * 1024);
    }
    for (int r = wave; r < BN / 16; r += 4) {
      int row = r * 16 + lrow;
      int lcb = (lq ^ ((row >> 1) & 3)) << 4;
      const char* src = (const char*)(Bt + (size_t)(tN + row) * K + kk) + lcb;
      gload16(src, (char*)Bs + r * 1024);
    }
    __syncthreads();

    bfrag8 af[MF], bfr[NF];
#pragma unroll
    for (int mi = 0; mi < MF; ++mi) {
      int row = wm * (MF * 16) + mi * 16 + fr;
      af[mi] = *(const bfrag8*)((const char*)As + row * 64 + ((kg ^ ((row >> 1) & 3)) << 4));
    }
#pragma unroll
    for (int ni = 0; ni < NF; ++ni) {
      int row = wn * (NF * 16) + ni * 16 + fr;
      bfr[ni] = *(const bfrag8*)((const char*)Bs + row * 64 + ((kg ^ ((row >> 1) & 3)) << 4));
    }
#pragma unroll
    for (int mi = 0; mi < MF; ++mi)
#pragma unroll
      for (int ni = 0; ni < NF; ++ni)
        acc[mi][ni] = __builtin_amdgcn_mfma_f32_16x16x32_bf16(af[mi], bfr[ni], acc[mi][ni], 0, 0, 0);
  }

  const int orow = tM + wm * (MF * 16), ocol = tN + wn * (NF * 16);
#pragma unroll
  for (int mi = 0; mi < MF; ++mi)
#pragma unroll
    for (int ni = 0; ni < NF; ++ni)
#pragma unroll
      for (int r = 0; r < 4; ++r) {
        int row = orow + mi * 16 + kg * 4 + r;
        int col = ocol + ni * 16 + fr;
        float v = acc[mi][ni][r];
        size_t idx = (size_t)row * N + col;
        if (EPI == 0)      C[idx] = v;
        else if (EPI == 1) C[idx] = softplusf_(v + bias[col]);
        else               atomicAdd(&C[idx], v);
      }
}

// ---------------- segmented selective scan (register-state, no LDS/shfl) ----------------
// One thread per channel; h[16],A[16] in VGPRs.
// b,d derived UNIFORMLY from blockIdx so B/C row addresses are provably
// wave-uniform -> scalar s_load broadcast (DI/256 == 8 exactly).
// Pass 1: local scan with h0=0; store P = prod(dA), Q = local h_end.
// pq layout: [P|Q][seg][NCH][DSZ]
__global__ __launch_bounds__(256) void scan_pass1(const float* __restrict__ delta,
                                                  const float* __restrict__ dbc,
                                                  const float* __restrict__ u,
                                                  const float* __restrict__ A_log,
                                                  float* __restrict__ pq) {
  const int b = blockIdx.x >> 3;                       // uniform
  const int d = ((blockIdx.x & 7) << 8) | threadIdx.x; // per-lane
  const int ch = blockIdx.x * 256 + threadIdx.x;
  const int seg = blockIdx.y;
  const size_t rb = (size_t)b * LL + (size_t)seg * TSEG;  // uniform
  float A[DSZ], h[DSZ], P[DSZ];
#pragma unroll
  for (int n = 0; n < DSZ; ++n) {
    A[n] = -__expf(A_log[d * DSZ + n]);
    h[n] = 0.f;
    P[n] = 1.f;
  }
  float dl = delta[rb * DI + d];
  float uu = u[rb * DI + d];
  for (int t = 0; t < TSEG; ++t) {
    float dln = 0.f, uun = 0.f;
    if (t + 1 < TSEG) {                 // register prefetch of next step
      dln = delta[(rb + t + 1) * DI + d];
      uun = u[(rb + t + 1) * DI + d];
    }
    const float* Brow = dbc + (rb + t) * 96 + DTR;   // uniform -> s_load
    const float dlu = dl * uu;
#pragma unroll
    for (int n = 0; n < DSZ; ++n) {
      float dA = __expf(dl * A[n]);
      h[n] = __builtin_fmaf(dA, h[n], dlu * Brow[n]);
      P[n] *= dA;
    }
    dl = dln; uu = uun;
  }
  const size_t base = ((size_t)seg * NCH + ch) * DSZ;
  float4* pP = (float4*)(pq + base);
  float4* pQ = (float4*)(pq + (size_t)SEG * NCH * DSZ + base);
#pragma unroll
  for (int q = 0; q < 4; ++q) {
    pP[q] = make_float4(P[4 * q], P[4 * q + 1], P[4 * q + 2], P[4 * q + 3]);
    pQ[q] = make_float4(h[4 * q], h[4 * q + 1], h[4 * q + 2], h[4 * q + 3]);
  }
}

// Prefix: per (channel, state): chain the SEG segment transfer functions.
__global__ __launch_bounds__(256) void scan_prefix(const float* __restrict__ pq,
                                                   float* __restrict__ hinit) {
  const int i = blockIdx.x * 256 + threadIdx.x;  // i = ch*DSZ + n
  const size_t stride = (size_t)NCH * DSZ;
  float h = 0.f;
#pragma unroll
  for (int s = 0; s < SEG; ++s) {
    hinit[(size_t)s * stride + i] = h;
    float P = pq[(size_t)s * stride + i];
    float Q = pq[(size_t)SEG * stride + (size_t)s * stride + i];
    h = __builtin_fmaf(P, h, Q);
  }
}

// Pass 2: true scan from h_init; y reduction fully in-register; fused epilogue.
__global__ __launch_bounds__(256) void scan_pass2(const float* __restrict__ delta,
                                                  const float* __restrict__ dbc,
                                                  const float* __restrict__ u,
                                                  const float* __restrict__ xr,
                                                  const float* __restrict__ A_log,
                                                  const float* __restrict__ Dv,
                                                  const float* __restrict__ hinit,
                                                  unsigned short* __restrict__ ybf) {
  const int b = blockIdx.x >> 3;                       // uniform
  const int d = ((blockIdx.x & 7) << 8) | threadIdx.x; // per-lane
  const int ch = blockIdx.x * 256 + threadIdx.x;
  const int seg = blockIdx.y;
  const size_t rb = (size_t)b * LL + (size_t)seg * TSEG;  // uniform
  float A[DSZ], h[DSZ];
#pragma unroll
  for (int n = 0; n < DSZ; ++n) A[n] = -__expf(A_log[d * DSZ + n]);
  {
    const float4* hp = (const float4*)(hinit + ((size_t)seg * NCH + ch) * DSZ);
#pragma unroll
    for (int q = 0; q < 4; ++q) {
      float4 v = hp[q];
      h[4 * q] = v.x; h[4 * q + 1] = v.y; h[4 * q + 2] = v.z; h[4 * q + 3] = v.w;
    }
  }
  const float Dd = Dv[d];
  float dl = delta[rb * DI + d];
  float uu = u[rb * DI + d];
  float rs = xr[rb * (2 * DI) + DI + d];
  for (int t = 0; t < TSEG; ++t) {
    float dln = 0.f, uun = 0.f, rsn = 0.f;
    if (t + 1 < TSEG) {
      dln = delta[(rb + t + 1) * DI + d];
      uun = u[(rb + t + 1) * DI + d];
      rsn = xr[(rb + t + 1) * (2 * DI) + DI + d];
    }
    const float* Brow = dbc + (rb + t) * 96 + DTR;   // uniform -> s_load
    const float* Crow = Brow + DSZ;
    const float dlu = dl * uu;
    float y = 0.f;
#pragma unroll
    for (int n = 0; n < DSZ; ++n) {
      float dA = __expf(dl * A[n]);
      h[n] = __builtin_fmaf(dA, h[n], dlu * Brow[n]);
      y = __builtin_fmaf(h[n], Crow[n], y);
    }
    float yv = (y + uu * Dd) * (rs * sigmoidf_(rs));
    ybf[(rb + t) * DI + d] = f2bf(yv);
    dl = dln; uu = uun; rs = rsn;
  }
}

// ---------------- launcher ----------------
extern "C" void kernel_launch(void* const* d_in, const int* in_sizes, int n_in,
                              void* d_out, int out_size, void* d_ws, size_t ws_size,
                              hipStream_t stream) {
  const float* x     = (const float*)d_in[0];
  const float* W_in  = (const float*)d_in[1];
  const float* convw = (const float*)d_in[2];
  const float* convb = (const float*)d_in[3];
  const float* W_x   = (const float*)d_in[4];
  const float* W_dt  = (const float*)d_in[5];
  const float* b_dt  = (const float*)d_in[6];
  const float* A_log = (const float*)d_in[7];
  const float* Dv    = (const float*)d_in[8];
  const float* W_out = (const float*)d_in[9];
  float* out = (float*)d_out;

  char* ws = (char*)d_ws;
  size_t off = 0;
  auto alloc = [&](size_t bytes) { char* p = ws + off; off += (bytes + 255) & ~(size_t)255; return p; };
  unsigned short* xbf   = (unsigned short*)alloc((size_t)MM * DM * 2);
  unsigned short* Wint  = (unsigned short*)alloc((size_t)(2 * DI) * DM * 2);
  float*          xr    = (float*)alloc((size_t)MM * (2 * DI) * 4);
  float*          uf    = (float*)alloc((size_t)MM * DI * 4);
  unsigned short* ubf   = (unsigned short*)alloc((size_t)MM * DI * 2);
  unsigned short* Wxt   = (unsigned short*)alloc((size_t)96 * DI * 2);
  float*          dbc   = (float*)alloc((size_t)MM * 96 * 4);
  unsigned short* drbf  = (unsigned short*)alloc((size_t)MM * DTR * 2);
  unsigned short* Wdtt  = (unsigned short*)alloc((size_t)DI * DTR * 2);
  float*          delta = (float*)alloc((size_t)MM * DI * 4);
  unsigned short* ybf   = (unsigned short*)alloc((size_t)MM * DI * 2);
  unsigned short* Woutt = (unsigned short*)alloc((size_t)DM * DI * 2);
  float*          pq    = (float*)alloc((size_t)2 * SEG * NCH * DSZ * 4);
  float*          hinit = (float*)alloc((size_t)SEG * NCH * DSZ * 4);

  cvt_bf16<<<(MM * DM / 4) / 256, 256, 0, stream>>>(x, xbf, MM * DM);
  transpose_cvt<<<dim3((2 * DI) / 32, DM / 32), dim3(32, 8), 0, stream>>>(W_in, Wint, DM, 2 * DI);
  transpose_cvt<<<dim3(96 / 32, DI / 32), dim3(32, 8), 0, stream>>>(W_x, Wxt, DI, 96);
  transpose_cvt<<<dim3(DI / 32, DTR / 32), dim3(32, 8), 0, stream>>>(W_dt, Wdtt, DTR, DI);
  transpose_cvt<<<dim3(DM / 32, DI / 32), dim3(32, 8), 0, stream>>>(W_out, Woutt, DI, DM);

  // xr = x @ W_in   (M=4096, N=4096, K=1024)
  gemm_bf16<128, 128, 2, 2, 4, 4, 0><<<dim3((2 * DI) / 128, MM / 128, 1), 256, 0, stream>>>(
      xbf, Wint, xr, nullptr, MM, 2 * DI, DM, DM);

  // u = silu(conv(xi))
  conv_silu<<<dim3(DI / 256, LL / 64, BB), 256, 0, stream>>>(xr, convw, convb, uf, ubf);

  // dbc = u @ W_x   (M=4096, N=96, K=2048) split-K=8
  hipMemsetAsync(dbc, 0, (size_t)MM * 96 * 4, stream);
  gemm_bf16<128, 96, 4, 1, 2, 6, 2><<<dim3(1, MM / 128, 8), 256, 0, stream>>>(
      ubf, Wxt, dbc, nullptr, MM, 96, DI, DI / 8);

  extract_dr<<<(MM * DTR) / 256, 256, 0, stream>>>(dbc, drbf);

  // delta = softplus(delta_r @ W_dt + b_dt)   (M=4096, N=2048, K=64)
  gemm_bf16<128, 128, 2, 2, 4, 4, 1><<<dim3(DI / 128, MM / 128, 1), 256, 0, stream>>>(
      drbf, Wdtt, delta, b_dt, MM, DI, DTR, DTR);

  // segmented selective scan (register-state)
  scan_pass1<<<dim3(NCH / 256, SEG), 256, 0, stream>>>(delta, dbc, uf, A_log, pq);
  scan_prefix<<<(NCH * DSZ) / 256, 256, 0, stream>>>(pq, hinit);
  scan_pass2<<<dim3(NCH / 256, SEG), 256, 0, stream>>>(delta, dbc, uf, xr, A_log, Dv, hinit, ybf);

  // out = y @ W_out   (M=4096, N=1024, K=2048)
  gemm_bf16<128, 128, 2, 2, 4, 4, 0><<<dim3(DM / 128, MM / 128, 1), 256, 0, stream>>>(
      ybf, Woutt, out, nullptr, MM, DM, DI, DI);
}

// Round 12
// 380.165 us; speedup vs baseline: 1.2376x; 1.0669x over previous
//
#include <hip/hip_runtime.h>

#define DM   1024
#define DI   2048
#define DSZ  16
#define DTR  64
#define BB   2
#define LL   2048
#define MM   (BB*LL)   // 4096
#define SEG  64
#define TSEG (LL/SEG)  // 32
#define NCH  (BB*DI)   // 4096 total channels

using bfrag8 = __attribute__((ext_vector_type(8))) short;
using facc4  = __attribute__((ext_vector_type(4))) float;

__device__ __forceinline__ unsigned short f2bf(float f) {
  unsigned int u = __float_as_uint(f);
  u += 0x7fffu + ((u >> 16) & 1u);
  return (unsigned short)(u >> 16);
}

__device__ __forceinline__ float sigmoidf_(float x) { return 1.f / (1.f + __expf(-x)); }
__device__ __forceinline__ float softplusf_(float x) { return (x > 20.f) ? x : log1pf(__expf(x)); }

__device__ __forceinline__ void gload16(const void* g, void* l) {
  __builtin_amdgcn_global_load_lds(
      (__attribute__((address_space(1))) void*)(g),
      (__attribute__((address_space(3))) void*)(l), 16, 0, 0);
}

// ---------------- elementwise converts ----------------

__global__ __launch_bounds__(256) void cvt_bf16(const float* __restrict__ s,
                                                unsigned short* __restrict__ d, int n) {
  int i = (blockIdx.x * 256 + threadIdx.x) * 4;
  if (i + 3 < n) {
    float4 v = *(const float4*)(s + i);
    ushort4 o;
    o.x = f2bf(v.x); o.y = f2bf(v.y); o.z = f2bf(v.z); o.w = f2bf(v.w);
    *(ushort4*)(d + i) = o;
  }
}

// src f32 [R][C] -> dst bf16 [C][R]; R,C multiples of 32
__global__ __launch_bounds__(256) void transpose_cvt(const float* __restrict__ src,
                                                     unsigned short* __restrict__ dst,
                                                     int R, int C) {
  __shared__ float tile[32][33];
  int c0 = blockIdx.x * 32, r0 = blockIdx.y * 32;
  for (int i = threadIdx.y; i < 32; i += 8)
    tile[i][threadIdx.x] = src[(size_t)(r0 + i) * C + c0 + threadIdx.x];
  __syncthreads();
  for (int i = threadIdx.y; i < 32; i += 8)
    dst[(size_t)(c0 + i) * R + r0 + threadIdx.x] = f2bf(tile[threadIdx.x][i]);
}

__global__ __launch_bounds__(256) void extract_dr(const float* __restrict__ dbc,
                                                  unsigned short* __restrict__ dr) {
  int i = blockIdx.x * 256 + threadIdx.x;
  if (i < MM * DTR) {
    int row = i >> 6, c = i & 63;
    dr[i] = f2bf(dbc[(size_t)row * 96 + c]);
  }
}

// ---------------- depthwise causal conv + silu ----------------
__global__ __launch_bounds__(256) void conv_silu(const float* __restrict__ xr,
                                                 const float* __restrict__ cw,
                                                 const float* __restrict__ cb,
                                                 float* __restrict__ uf,
                                                 unsigned short* __restrict__ ubf) {
  const int d = blockIdx.x * 256 + threadIdx.x;
  const int b = blockIdx.z;
  const int t0 = blockIdx.y * 64;
  const float w0 = cw[d * 4 + 0], w1 = cw[d * 4 + 1], w2 = cw[d * 4 + 2], w3 = cw[d * 4 + 3];
  const float bias = cb[d];
  const size_t base = ((size_t)b * LL) * (2 * DI) + d;
  float xm3 = (t0 >= 3) ? xr[base + (size_t)(t0 - 3) * (2 * DI)] : 0.f;
  float xm2 = (t0 >= 2) ? xr[base + (size_t)(t0 - 2) * (2 * DI)] : 0.f;
  float xm1 = (t0 >= 1) ? xr[base + (size_t)(t0 - 1) * (2 * DI)] : 0.f;
  for (int t = t0; t < t0 + 64; ++t) {
    float x0 = xr[base + (size_t)t * (2 * DI)];
    float a = bias + w0 * xm3 + w1 * xm2 + w2 * xm1 + w3 * x0;
    float uu = a * sigmoidf_(a);
    size_t oi = ((size_t)b * LL + t) * DI + d;
    uf[oi] = uu;
    ubf[oi] = f2bf(uu);
    xm3 = xm2; xm2 = xm1; xm1 = x0;
  }
}

// ---------------- bf16 MFMA GEMM:  C[M][N] = A[M][K] * Bt[N][K]^T ----------------
// EPI: 0 = store f32; 1 = softplus(v + bias[col]); 2 = atomicAdd (split-K)
template<int BM, int BN, int WMN, int WNN, int MF, int NF, int EPI>
__global__ __launch_bounds__(256, 2) void gemm_bf16(const unsigned short* __restrict__ A,
                                                    const unsigned short* __restrict__ Bt,
                                                    float* __restrict__ C,
                                                    const float* __restrict__ bias,
                                                    int M, int N, int K, int kLen) {
  static_assert(WMN * WNN == 4 && WMN * MF * 16 == BM && WNN * NF * 16 == BN, "geom");
  __shared__ unsigned short smem[(BM + BN) * 32];
  unsigned short* As = smem;
  unsigned short* Bs = smem + BM * 32;
  const int tid = threadIdx.x;
  const int wave = tid >> 6, lane = tid & 63;
  const int tM = blockIdx.y * BM, tN = blockIdx.x * BN;
  const int k0 = blockIdx.z * kLen;
  const int lrow = lane >> 2, lq = lane & 3;
  const int wm = wave / WNN, wn = wave % WNN;
  const int fr = lane & 15, kg = lane >> 4;

  facc4 acc[MF][NF];
#pragma unroll
  for (int mi = 0; mi < MF; ++mi)
#pragma unroll
    for (int ni = 0; ni < NF; ++ni)
#pragma unroll
      for (int r = 0; r < 4; ++r) acc[mi][ni][r] = 0.f;

  for (int kk = k0; kk < k0 + kLen; kk += 32) {
    __syncthreads();
    for (int r = wave; r < BM / 16; r += 4) {
      int row = r * 16 + lrow;
      int lcb = (lq ^ ((row >> 1) & 3)) << 4;
      const char* src = (const char*)(A + (size_t)(tM + row) * K + kk) + lcb;
      gload16(src, (char*)As + r * 1024);
    }
    for (int r = wave; r < BN / 16; r += 4) {
      int row = r * 16 + lrow;
      int lcb = (lq ^ ((row >> 1) & 3)) << 4;
      const char* src = (const char*)(Bt + (size_t)(tN + row) * K + kk) + lcb;
      gload16(src, (char*)Bs + r * 1024);
    }
    __syncthreads();

    bfrag8 af[MF], bfr[NF];
#pragma unroll
    for (int mi = 0; mi < MF; ++mi) {
      int row = wm * (MF * 16) + mi * 16 + fr;
      af[mi] = *(const bfrag8*)((const char*)As + row * 64 + ((kg ^ ((row >> 1) & 3)) << 4));
    }
#pragma unroll
    for (int ni = 0; ni < NF; ++ni) {
      int row = wn * (NF * 16) + ni * 16 + fr;
      bfr[ni] = *(const bfrag8*)((const char*)Bs + row * 64 + ((kg ^ ((row >> 1) & 3)) << 4));
    }
#pragma unroll
    for (int mi = 0; mi < MF; ++mi)
#pragma unroll
      for (int ni = 0; ni < NF; ++ni)
        acc[mi][ni] = __builtin_amdgcn_mfma_f32_16x16x32_bf16(af[mi], bfr[ni], acc[mi][ni], 0, 0, 0);
  }

  const int orow = tM + wm * (MF * 16), ocol = tN + wn * (NF * 16);
#pragma unroll
  for (int mi = 0; mi < MF; ++mi)
#pragma unroll
    for (int ni = 0; ni < NF; ++ni)
#pragma unroll
      for (int r = 0; r < 4; ++r) {
        int row = orow + mi * 16 + kg * 4 + r;
        int col = ocol + ni * 16 + fr;
        float v = acc[mi][ni][r];
        size_t idx = (size_t)row * N + col;
        if (EPI == 0)      C[idx] = v;
        else if (EPI == 1) C[idx] = softplusf_(v + bias[col]);
        else               atomicAdd(&C[idx], v);
      }
}

// ---------------- segmented selective scan (register-state, no LDS/shfl) ----------------
// One thread per channel; h[16],A[16] in VGPRs; B/C rows wave-uniform -> s_load.
// Double-buffered B/C prefetch (static indices), 2x-unrolled time loop.
// Pass 1: local scan with h0=0; store P = prod(dA), Q = local h_end.
// pq layout: [P|Q][seg][NCH][DSZ]
__global__ __launch_bounds__(256) void scan_pass1(const float* __restrict__ delta,
                                                  const float* __restrict__ dbc,
                                                  const float* __restrict__ u,
                                                  const float* __restrict__ A_log,
                                                  float* __restrict__ pq) {
  const int b = blockIdx.x >> 3;                       // uniform
  const int d = ((blockIdx.x & 7) << 8) | threadIdx.x; // per-lane
  const int ch = blockIdx.x * 256 + threadIdx.x;
  const int seg = blockIdx.y;
  const size_t rb = (size_t)b * LL + (size_t)seg * TSEG;  // uniform
  float A[DSZ], h[DSZ], P[DSZ], Ba[DSZ], Bb[DSZ];
#pragma unroll
  for (int n = 0; n < DSZ; ++n) {
    A[n] = -__expf(A_log[d * DSZ + n]);
    h[n] = 0.f;
    P[n] = 1.f;
  }
  float dl = delta[rb * DI + d];
  float uu = u[rb * DI + d];
  {
    const float* B0 = dbc + rb * 96 + DTR;   // uniform -> s_load
#pragma unroll
    for (int n = 0; n < DSZ; ++n) Ba[n] = B0[n];
  }
  for (int t = 0; t < TSEG; t += 2) {
    // prefetch t+1 (always valid: TSEG even)
    float dl1 = delta[(rb + t + 1) * DI + d];
    float uu1 = u[(rb + t + 1) * DI + d];
    {
      const float* B1 = dbc + (rb + t + 1) * 96 + DTR;
#pragma unroll
      for (int n = 0; n < DSZ; ++n) Bb[n] = B1[n];
    }
    {  // step t (dl, uu, Ba)
      const float dlu = dl * uu;
#pragma unroll
      for (int n = 0; n < DSZ; ++n) {
        float dA = __expf(dl * A[n]);
        h[n] = __builtin_fmaf(dA, h[n], dlu * Ba[n]);
        P[n] *= dA;
      }
    }
    // prefetch t+2
    if (t + 2 < TSEG) {
      dl = delta[(rb + t + 2) * DI + d];
      uu = u[(rb + t + 2) * DI + d];
      const float* B2 = dbc + (rb + t + 2) * 96 + DTR;
#pragma unroll
      for (int n = 0; n < DSZ; ++n) Ba[n] = B2[n];
    }
    {  // step t+1 (dl1, uu1, Bb)
      const float dlu = dl1 * uu1;
#pragma unroll
      for (int n = 0; n < DSZ; ++n) {
        float dA = __expf(dl1 * A[n]);
        h[n] = __builtin_fmaf(dA, h[n], dlu * Bb[n]);
        P[n] *= dA;
      }
    }
  }
  const size_t base = ((size_t)seg * NCH + ch) * DSZ;
  float4* pP = (float4*)(pq + base);
  float4* pQ = (float4*)(pq + (size_t)SEG * NCH * DSZ + base);
#pragma unroll
  for (int q = 0; q < 4; ++q) {
    pP[q] = make_float4(P[4 * q], P[4 * q + 1], P[4 * q + 2], P[4 * q + 3]);
    pQ[q] = make_float4(h[4 * q], h[4 * q + 1], h[4 * q + 2], h[4 * q + 3]);
  }
}

// Prefix: per (channel, state): chain the SEG segment transfer functions.
__global__ __launch_bounds__(256) void scan_prefix(const float* __restrict__ pq,
                                                   float* __restrict__ hinit) {
  const int i = blockIdx.x * 256 + threadIdx.x;  // i = ch*DSZ + n
  const size_t stride = (size_t)NCH * DSZ;
  float h = 0.f;
#pragma unroll
  for (int s = 0; s < SEG; ++s) {
    hinit[(size_t)s * stride + i] = h;
    float P = pq[(size_t)s * stride + i];
    float Q = pq[(size_t)SEG * stride + (size_t)s * stride + i];
    h = __builtin_fmaf(P, h, Q);
  }
}

// Pass 2: true scan from h_init; y reduction fully in-register; fused epilogue.
__global__ __launch_bounds__(256) void scan_pass2(const float* __restrict__ delta,
                                                  const float* __restrict__ dbc,
                                                  const float* __restrict__ u,
                                                  const float* __restrict__ xr,
                                                  const float* __restrict__ A_log,
                                                  const float* __restrict__ Dv,
                                                  const float* __restrict__ hinit,
                                                  unsigned short* __restrict__ ybf) {
  const int b = blockIdx.x >> 3;                       // uniform
  const int d = ((blockIdx.x & 7) << 8) | threadIdx.x; // per-lane
  const int ch = blockIdx.x * 256 + threadIdx.x;
  const int seg = blockIdx.y;
  const size_t rb = (size_t)b * LL + (size_t)seg * TSEG;  // uniform
  float A[DSZ], h[DSZ], Ba[DSZ], Bb[DSZ], Ca[DSZ], Cb[DSZ];
#pragma unroll
  for (int n = 0; n < DSZ; ++n) A[n] = -__expf(A_log[d * DSZ + n]);
  {
    const float4* hp = (const float4*)(hinit + ((size_t)seg * NCH + ch) * DSZ);
#pragma unroll
    for (int q = 0; q < 4; ++q) {
      float4 v = hp[q];
      h[4 * q] = v.x; h[4 * q + 1] = v.y; h[4 * q + 2] = v.z; h[4 * q + 3] = v.w;
    }
  }
  const float Dd = Dv[d];
  float dl = delta[rb * DI + d];
  float uu = u[rb * DI + d];
  float rs = xr[rb * (2 * DI) + DI + d];
  {
    const float* B0 = dbc + rb * 96 + DTR;   // uniform -> s_load
#pragma unroll
    for (int n = 0; n < DSZ; ++n) { Ba[n] = B0[n]; Ca[n] = B0[DSZ + n]; }
  }
  for (int t = 0; t < TSEG; t += 2) {
    // prefetch t+1 (always valid: TSEG even)
    float dl1 = delta[(rb + t + 1) * DI + d];
    float uu1 = u[(rb + t + 1) * DI + d];
    float rs1 = xr[(rb + t + 1) * (2 * DI) + DI + d];
    {
      const float* B1 = dbc + (rb + t + 1) * 96 + DTR;
#pragma unroll
      for (int n = 0; n < DSZ; ++n) { Bb[n] = B1[n]; Cb[n] = B1[DSZ + n]; }
    }
    {  // step t
      const float dlu = dl * uu;
      float y = 0.f;
#pragma unroll
      for (int n = 0; n < DSZ; ++n) {
        float dA = __expf(dl * A[n]);
        h[n] = __builtin_fmaf(dA, h[n], dlu * Ba[n]);
        y = __builtin_fmaf(h[n], Ca[n], y);
      }
      float yv = (y + uu * Dd) * (rs * sigmoidf_(rs));
      ybf[(rb + t) * DI + d] = f2bf(yv);
    }
    // prefetch t+2
    if (t + 2 < TSEG) {
      dl = delta[(rb + t + 2) * DI + d];
      uu = u[(rb + t + 2) * DI + d];
      rs = xr[(rb + t + 2) * (2 * DI) + DI + d];
      const float* B2 = dbc + (rb + t + 2) * 96 + DTR;
#pragma unroll
      for (int n = 0; n < DSZ; ++n) { Ba[n] = B2[n]; Ca[n] = B2[DSZ + n]; }
    }
    {  // step t+1
      const float dlu = dl1 * uu1;
      float y = 0.f;
#pragma unroll
      for (int n = 0; n < DSZ; ++n) {
        float dA = __expf(dl1 * A[n]);
        h[n] = __builtin_fmaf(dA, h[n], dlu * Bb[n]);
        y = __builtin_fmaf(h[n], Cb[n], y);
      }
      float yv = (y + uu1 * Dd) * (rs1 * sigmoidf_(rs1));
      ybf[(rb + t + 1) * DI + d] = f2bf(yv);
    }
  }
}

// ---------------- launcher ----------------
extern "C" void kernel_launch(void* const* d_in, const int* in_sizes, int n_in,
                              void* d_out, int out_size, void* d_ws, size_t ws_size,
                              hipStream_t stream) {
  const float* x     = (const float*)d_in[0];
  const float* W_in  = (const float*)d_in[1];
  const float* convw = (const float*)d_in[2];
  const float* convb = (const float*)d_in[3];
  const float* W_x   = (const float*)d_in[4];
  const float* W_dt  = (const float*)d_in[5];
  const float* b_dt  = (const float*)d_in[6];
  const float* A_log = (const float*)d_in[7];
  const float* Dv    = (const float*)d_in[8];
  const float* W_out = (const float*)d_in[9];
  float* out = (float*)d_out;

  char* ws = (char*)d_ws;
  size_t off = 0;
  auto alloc = [&](size_t bytes) { char* p = ws + off; off += (bytes + 255) & ~(size_t)255; return p; };
  unsigned short* xbf   = (unsigned short*)alloc((size_t)MM * DM * 2);
  unsigned short* Wint  = (unsigned short*)alloc((size_t)(2 * DI) * DM * 2);
  float*          xr    = (float*)alloc((size_t)MM * (2 * DI) * 4);
  float*          uf    = (float*)alloc((size_t)MM * DI * 4);
  unsigned short* ubf   = (unsigned short*)alloc((size_t)MM * DI * 2);
  unsigned short* Wxt   = (unsigned short*)alloc((size_t)96 * DI * 2);
  float*          dbc   = (float*)alloc((size_t)MM * 96 * 4);
  unsigned short* drbf  = (unsigned short*)alloc((size_t)MM * DTR * 2);
  unsigned short* Wdtt  = (unsigned short*)alloc((size_t)DI * DTR * 2);
  float*          delta = (float*)alloc((size_t)MM * DI * 4);
  unsigned short* ybf   = (unsigned short*)alloc((size_t)MM * DI * 2);
  unsigned short* Woutt = (unsigned short*)alloc((size_t)DM * DI * 2);
  float*          pq    = (float*)alloc((size_t)2 * SEG * NCH * DSZ * 4);
  // hinit (SEG*NCH*DSZ*4 = 16.8 MB) aliases xbf+Wint (24 MB): both are dead
  // after GEMM1, which completes before scan_prefix writes hinit; both are
  // fully rewritten at the start of every call before GEMM1 reads them.
  float*          hinit = (float*)ws;

  cvt_bf16<<<(MM * DM / 4) / 256, 256, 0, stream>>>(x, xbf, MM * DM);
  transpose_cvt<<<dim3((2 * DI) / 32, DM / 32), dim3(32, 8), 0, stream>>>(W_in, Wint, DM, 2 * DI);
  transpose_cvt<<<dim3(96 / 32, DI / 32), dim3(32, 8), 0, stream>>>(W_x, Wxt, DI, 96);
  transpose_cvt<<<dim3(DI / 32, DTR / 32), dim3(32, 8), 0, stream>>>(W_dt, Wdtt, DTR, DI);
  transpose_cvt<<<dim3(DM / 32, DI / 32), dim3(32, 8), 0, stream>>>(W_out, Woutt, DI, DM);

  // xr = x @ W_in   (M=4096, N=4096, K=1024)
  gemm_bf16<128, 128, 2, 2, 4, 4, 0><<<dim3((2 * DI) / 128, MM / 128, 1), 256, 0, stream>>>(
      xbf, Wint, xr, nullptr, MM, 2 * DI, DM, DM);

  // u = silu(conv(xi))
  conv_silu<<<dim3(DI / 256, LL / 64, BB), 256, 0, stream>>>(xr, convw, convb, uf, ubf);

  // dbc = u @ W_x   (M=4096, N=96, K=2048) split-K=8
  hipMemsetAsync(dbc, 0, (size_t)MM * 96 * 4, stream);
  gemm_bf16<128, 96, 4, 1, 2, 6, 2><<<dim3(1, MM / 128, 8), 256, 0, stream>>>(
      ubf, Wxt, dbc, nullptr, MM, 96, DI, DI / 8);

  extract_dr<<<(MM * DTR) / 256, 256, 0, stream>>>(dbc, drbf);

  // delta = softplus(delta_r @ W_dt + b_dt)   (M=4096, N=2048, K=64)
  gemm_bf16<128, 128, 2, 2, 4, 4, 1><<<dim3(DI / 128, MM / 128, 1), 256, 0, stream>>>(
      drbf, Wdtt, delta, b_dt, MM, DI, DTR, DTR);

  // segmented selective scan (register-state, SEG=64)
  scan_pass1<<<dim3(NCH / 256, SEG), 256, 0, stream>>>(delta, dbc, uf, A_log, pq);
  scan_prefix<<<(NCH * DSZ) / 256, 256, 0, stream>>>(pq, hinit);
  scan_pass2<<<dim3(NCH / 256, SEG), 256, 0, stream>>>(delta, dbc, uf, xr, A_log, Dv, hinit, ybf);

  // out = y @ W_out   (M=4096, N=1024, K=2048)
  gemm_bf16<128, 128, 2, 2, 4, 4, 0><<<dim3(DM / 128, MM / 128, 1), 256, 0, stream>>>(
      ybf, Woutt, out, nullptr, MM, DM, DI, DI);
}